// Round 2
// baseline (355.627 us; speedup 1.0000x reference)
//
#include <hip/hip_runtime.h>
#include <hip/hip_cooperative_groups.h>
#include <math.h>

namespace cg = cooperative_groups;

// Segment-sum out[src[e], f] += edge_w[e][f], E=3.2M, N=100k, F=16.
//
// R1 analysis: top-5 rocprof dispatches are all ~121us 819MB ws-poison
// fills -> (a) each of our kernels < 121us, (b) 352us total only closes if
// one fill is inside the timed region -> our budget ~230us, and we get NO
// per-kernel counters until the main work is a single >127us dispatch.
// => Fuse bin->acc->decode into ONE cooperative kernel (visibility +
// removes launch gaps) and fix two modeled acc serializations:
//   - per-slice cnt scalar-load chain -> preload ksh[SLICES2] into LDS
//   - 1-iteration inner loop (no ILP) -> uniform first-tranche pass with
//     unconditional clamped loads, 8-slice unroll (8 gathers in flight),
//     predicated DS atomic; rare second tranche in a cheap pass2.
// Bin: 512 bins on the 512-block grid (2 blocks/CU, 16 waves vs 8) +
// int2 src loads. Quantized u64 LDS accumulate (integer = order-invariant,
// deterministic); overflow past capb spills via fabric atomics.

#define F 16
#define NPB 1024
#define NPB_SHIFT 10
#define MAXB 128
#define SCALE 256.0f
#define INV_SCALE (1.0f / 256.0f)

// ---- fallback (R6-verified) config ----
#define NBIN 256
#define BINT 512
#define NSPLIT 8
#define SLICES (NBIN / NSPLIT)
#define ACCT 512

// ---- fused config ----
#define FB 512                       // grid blocks (2/CU on 256 CUs)
#define FT 512                       // threads per block
#define NBIN2 512                    // bin regions == FB
#define NSPLIT2 8
#define SLICES2 (NBIN2 / NSPLIT2)    // 64

__device__ __forceinline__ unsigned long long qpack(float4 v) {
    long long q0 = (long long)__float2int_rn(v.x * SCALE);
    long long q1 = (long long)__float2int_rn(v.y * SCALE);
    long long q2 = (long long)__float2int_rn(v.z * SCALE);
    long long q3 = (long long)__float2int_rn(v.w * SCALE);
    return (unsigned long long)((q3 << 48) + (q2 << 32) + (q1 << 16) + q0);
}

// ================================================================ fused
__global__ __launch_bounds__(FT, 4) void spmm_fused(
    const int* __restrict__ src,
    const float* __restrict__ w,
    unsigned int* __restrict__ idbuf,        // [NBIN2][B][capb]
    unsigned int* __restrict__ cnt,          // [NBIN2][B]
    unsigned long long* __restrict__ pbuf,   // [NSPLIT2+1][n4], last = spill
    float* __restrict__ out,
    int E, int B, int capb, int per_block, int N)
{
    __shared__ unsigned long long acc[NPB * 4];  // 32 KB
    __shared__ unsigned int pos[MAXB];
    __shared__ unsigned int ksh[SLICES2];

    cg::grid_group grid = cg::this_grid();
    const int tid = threadIdx.x;
    const int bid = blockIdx.x;
    const int n4  = N * 4;
    unsigned long long* spill = pbuf + (size_t)NSPLIT2 * (size_t)n4;

    // ---------------- phase 1: bin ----------------
    for (int i = tid; i < B; i += FT) pos[i] = 0;
    __syncthreads();

    const int lo = bid * per_block;
    const int hi = min(E, lo + per_block);
    for (int e = lo + tid * 2; e < hi; e += FT * 2) {
        int sa, sb = -1;
        if (e + 1 < hi) { int2 s2 = *(const int2*)(src + e); sa = s2.x; sb = s2.y; }
        else            { sa = src[e]; }
        {
            const int bk = sa >> NPB_SHIFT;
            const unsigned int off = (unsigned int)(sa & (NPB - 1));
            const unsigned int r = atomicAdd(&pos[bk], 1u);
            if (r < (unsigned int)capb) {
                idbuf[((size_t)bid * B + bk) * capb + r] = (off << 22) | (unsigned int)e;
            } else {
                const float4* wr = (const float4*)(w + (size_t)e * F);
                #pragma unroll
                for (int qq = 0; qq < 4; ++qq)
                    atomicAdd(&spill[(size_t)sa * 4 + qq], qpack(wr[qq]));
            }
        }
        if (sb >= 0) {
            const int e1 = e + 1;
            const int bk = sb >> NPB_SHIFT;
            const unsigned int off = (unsigned int)(sb & (NPB - 1));
            const unsigned int r = atomicAdd(&pos[bk], 1u);
            if (r < (unsigned int)capb) {
                idbuf[((size_t)bid * B + bk) * capb + r] = (off << 22) | (unsigned int)e1;
            } else {
                const float4* wr = (const float4*)(w + (size_t)e1 * F);
                #pragma unroll
                for (int qq = 0; qq < 4; ++qq)
                    atomicAdd(&spill[(size_t)sb * 4 + qq], qpack(wr[qq]));
            }
        }
    }
    __syncthreads();
    for (int i = tid; i < B; i += FT)
        cnt[bid * B + i] = min(pos[i], (unsigned int)capb);

    __threadfence();   // device-scope: idbuf/cnt visible cross-XCD
    grid.sync();

    // ---------------- phase 2: acc (task loop over B*NSPLIT2) ----------------
    const int q    = tid & 3;         // feature quad
    const int ei   = tid >> 2;        // 0..127
    const int half = ei >> 6;         // 0/1: which slice of the pair
    const int e64  = ei & 63;         // slot within slice

    for (int t = bid; t < B * NSPLIT2; t += FB) {
        const int b  = t >> 3;
        const int sp = t & 7;

        for (int i = tid; i < NPB * 4; i += FT) acc[i] = 0ULL;
        if (tid < SLICES2) ksh[tid] = cnt[(sp * SLICES2 + tid) * B + b];
        __syncthreads();

        // pass1: first 64 slots of every slice; uniform trips, 8-deep ILP.
        for (int sl = 0; sl < SLICES2; sl += 16) {
            unsigned int ent[8];
            #pragma unroll
            for (int j = 0; j < 8; ++j) {
                const int s = sl + 2 * j + half;
                ent[j] = idbuf[((size_t)(sp * SLICES2 + s) * B + b) * capb + e64];
            }
            float4 vv[8];
            #pragma unroll
            for (int j = 0; j < 8; ++j) {
                unsigned int e = ent[j] & 0x3FFFFFu;
                e = min(e, (unsigned int)(E - 1));     // garbage-safe clamp
                vv[j] = *(const float4*)(w + (size_t)e * F + q * 4);
            }
            #pragma unroll
            for (int j = 0; j < 8; ++j) {
                const int s = sl + 2 * j + half;
                if ((unsigned int)e64 < ksh[s]) {
                    const unsigned int off = ent[j] >> 22;
                    atomicAdd(&acc[off * 4 + q], qpack(vv[j]));
                }
            }
        }
        // pass2: rare slots >= 64 (k in [64, capb))
        for (int s = half; s < SLICES2; s += 2) {
            const unsigned int k = ksh[s];
            for (unsigned int i = 64 + e64; i < k; i += 64) {
                const unsigned int entry =
                    idbuf[((size_t)(sp * SLICES2 + s) * B + b) * capb + i];
                const unsigned int off = entry >> 22;
                const unsigned int e   = entry & 0x3FFFFFu;
                const float4 v = *(const float4*)(w + (size_t)e * F + q * 4);
                atomicAdd(&acc[off * 4 + q], qpack(v));
            }
        }
        __syncthreads();

        const int nbase = b << NPB_SHIFT;
        const int lim = min(NPB, N - nbase);
        unsigned long long* dst = pbuf + (size_t)sp * n4 + (size_t)nbase * 4;
        for (int i = tid; i < lim * 4; i += FT) dst[i] = acc[i];
        __syncthreads();
    }

    __threadfence();
    grid.sync();

    // ---------------- phase 3: decode ----------------
    for (int idx = bid * FT + tid; idx < n4; idx += FB * FT) {
        unsigned long long a = 0;
        #pragma unroll
        for (int s = 0; s < NSPLIT2 + 1; ++s) a += pbuf[(size_t)s * n4 + idx];
        long long tt = (long long)a;
        const int s0 = (int)(short)(tt & 0xffff);  tt = (tt - s0) >> 16;
        const int s1 = (int)(short)(tt & 0xffff);  tt = (tt - s1) >> 16;
        const int s2 = (int)(short)(tt & 0xffff);  tt = (tt - s2) >> 16;
        const int s3 = (int)(short)(tt & 0xffff);
        float4 o;
        o.x = (float)s0 * INV_SCALE;
        o.y = (float)s1 * INV_SCALE;
        o.z = (float)s2 * INV_SCALE;
        o.w = (float)s3 * INV_SCALE;
        ((float4*)out)[idx] = o;
    }
}

// ======================================================= fallback kernels
__global__ __launch_bounds__(BINT) void spmm_bin_id(
    const int* __restrict__ src,
    const float* __restrict__ w,
    unsigned int* __restrict__ idbuf,
    unsigned int* __restrict__ cnt,
    unsigned long long* __restrict__ spill,
    int E, int B, int capb, int per_block)
{
    __shared__ unsigned int pos[MAXB];
    const int tid = threadIdx.x;
    for (int i = tid; i < B; i += BINT) pos[i] = 0;
    __syncthreads();

    const int lo = blockIdx.x * per_block;
    const int hi = min(E, lo + per_block);

    for (int e = lo + tid; e < hi; e += BINT) {
        const int s = src[e];
        const int bk = s >> NPB_SHIFT;
        const unsigned int off = (unsigned int)(s & (NPB - 1));
        const unsigned int r = atomicAdd(&pos[bk], 1u);
        if (r < (unsigned int)capb) {
            idbuf[((size_t)blockIdx.x * B + bk) * capb + r] =
                (off << 22) | (unsigned int)e;
        } else {
            const float4* wr = (const float4*)(w + (size_t)e * F);
            #pragma unroll
            for (int q = 0; q < 4; ++q)
                atomicAdd(&spill[(size_t)s * 4 + q], qpack(wr[q]));
        }
    }
    __syncthreads();
    for (int i = tid; i < B; i += BINT)
        cnt[blockIdx.x * B + i] = min(pos[i], (unsigned int)capb);
}

__global__ __launch_bounds__(ACCT) void spmm_acc_g(
    const float* __restrict__ w,
    const unsigned int* __restrict__ idbuf,
    const unsigned int* __restrict__ cnt,
    unsigned long long* __restrict__ pbuf,
    int B, int capb, int N)
{
    __shared__ unsigned long long acc[NPB * 4];
    const int tid = threadIdx.x;
    const int b  = blockIdx.x >> 3;
    const int sp = blockIdx.x & 7;

    for (int i = tid; i < NPB * 4; i += ACCT) acc[i] = 0ULL;
    __syncthreads();

    const int q  = tid & 3;
    const int ei = tid >> 2;

    for (int sl = 0; sl < SLICES; ++sl) {
        const int blk = sp * SLICES + sl;
        const unsigned int k = cnt[blk * B + b];
        const unsigned int* base = idbuf + ((size_t)blk * B + b) * capb;
        for (unsigned int i = ei; i < k; i += ACCT / 4) {
            const unsigned int entry = base[i];
            const unsigned int off = entry >> 22;
            const unsigned int e   = entry & 0x3FFFFFu;
            const float4 v = *(const float4*)(w + (size_t)e * F + q * 4);
            atomicAdd(&acc[off * 4 + q], qpack(v));
        }
    }
    __syncthreads();

    const int nbase = b << NPB_SHIFT;
    const int lim = min(NPB, N - nbase);
    unsigned long long* dst = pbuf + (size_t)sp * ((size_t)N * 4) + (size_t)nbase * 4;
    for (int i = tid; i < lim * 4; i += ACCT) dst[i] = acc[i];
}

__global__ __launch_bounds__(256) void spmm_decode9(
    const unsigned long long* __restrict__ pbuf,
    float* __restrict__ out, int n4)
{
    const int idx = blockIdx.x * 256 + threadIdx.x;
    if (idx >= n4) return;
    unsigned long long a = 0;
    #pragma unroll
    for (int s = 0; s < NSPLIT + 1; ++s) a += pbuf[(size_t)s * n4 + idx];

    long long t = (long long)a;
    const int s0 = (int)(short)(t & 0xffff);  t = (t - s0) >> 16;
    const int s1 = (int)(short)(t & 0xffff);  t = (t - s1) >> 16;
    const int s2 = (int)(short)(t & 0xffff);  t = (t - s2) >> 16;
    const int s3 = (int)(short)(t & 0xffff);

    float4 o;
    o.x = (float)s0 * INV_SCALE;
    o.y = (float)s1 * INV_SCALE;
    o.z = (float)s2 * INV_SCALE;
    o.w = (float)s3 * INV_SCALE;
    ((float4*)out)[idx] = o;
}

__global__ __launch_bounds__(256) void spmm_scatter_gs(
    const int* __restrict__ src,
    const float* __restrict__ w,
    unsigned long long* __restrict__ ws,
    int total)
{
    const int stride = gridDim.x * blockDim.x;
    for (int idx = blockIdx.x * blockDim.x + threadIdx.x; idx < total; idx += stride) {
        const int e = idx >> 2, lane = idx & 3;
        const float4 v = ((const float4*)w)[idx];
        atomicAdd(&ws[src[e] * 4 + lane], qpack(v));
    }
}

__global__ __launch_bounds__(256) void spmm_decode1(
    const unsigned long long* __restrict__ ws,
    float* __restrict__ out, int n4)
{
    const int idx = blockIdx.x * 256 + threadIdx.x;
    if (idx >= n4) return;
    long long t = (long long)ws[idx];
    const int s0 = (int)(short)(t & 0xffff);  t = (t - s0) >> 16;
    const int s1 = (int)(short)(t & 0xffff);  t = (t - s1) >> 16;
    const int s2 = (int)(short)(t & 0xffff);  t = (t - s2) >> 16;
    const int s3 = (int)(short)(t & 0xffff);
    float4 o;
    o.x = (float)s0 * INV_SCALE;
    o.y = (float)s1 * INV_SCALE;
    o.z = (float)s2 * INV_SCALE;
    o.w = (float)s3 * INV_SCALE;
    ((float4*)out)[idx] = o;
}

// ---------------------------------------------------------------- launch
extern "C" void kernel_launch(void* const* d_in, const int* in_sizes, int n_in,
                              void* d_out, int out_size, void* d_ws, size_t ws_size,
                              hipStream_t stream) {
    const int* edge = (const int*)d_in[0];    // (2, E) -- row 0 is src
    const float* ew = (const float*)d_in[1];  // (E, 16)
    const int E = in_sizes[0] / 2;
    const int N = out_size / F;
    const int n4 = N * 4;
    float* out = (float*)d_out;

    const int B = (N + NPB - 1) >> NPB_SHIFT;  // 98

    // one-time cooperative-capability probe (host-only; capture-safe)
    static int coop_state = -1;
    if (coop_state < 0) {
        int maxb = 0, cus = 0;
        hipDeviceProp_t prop;
        int dev = 0;
        hipError_t e1 = hipGetDevice(&dev);
        hipError_t e2 = hipGetDeviceProperties(&prop, dev);
        if (e2 == hipSuccess) cus = prop.multiProcessorCount;
        hipError_t e3 = hipOccupancyMaxActiveBlocksPerMultiprocessor(
            &maxb, spmm_fused, FT, 0);
        coop_state = (e1 == hipSuccess && e3 == hipSuccess &&
                      (long)maxb * (long)cus >= FB) ? 1 : 0;
    }

    // ---- fused path layout ----
    const double mean2 = (double)E / ((double)NBIN2 * (double)B);   // ~63.8
    int capb2 = (int)(mean2 + 8.0 * sqrt(mean2 > 1.0 ? mean2 : 1.0) + 16.0);
    capb2 = (capb2 + 15) & ~15;                                     // ~144
    const size_t idbuf2_b = (size_t)NBIN2 * B * capb2 * 4;          // ~28.9 MB
    size_t off_cnt2  = (idbuf2_b + 255) & ~(size_t)255;
    const size_t cnt2_b = (size_t)NBIN2 * B * 4;
    size_t off_pbuf2 = (off_cnt2 + cnt2_b + 255) & ~(size_t)255;
    const size_t pbuf2_b = (size_t)(NSPLIT2 + 1) * n4 * 8;          // ~28.8 MB
    const size_t need2 = off_pbuf2 + pbuf2_b;

    // ---- fallback binned layout ----
    const double mean = (double)E / ((double)NBIN * (double)B);
    int capb = (int)(mean + 8.0 * sqrt(mean > 1.0 ? mean : 1.0) + 16.0);
    capb = (capb + 15) & ~15;
    const size_t idbuf_b = (size_t)NBIN * B * capb * 4;
    size_t off_cnt  = (idbuf_b + 255) & ~(size_t)255;
    const size_t cnt_b = (size_t)NBIN * B * 4;
    size_t off_pbuf = (off_cnt + cnt_b + 255) & ~(size_t)255;
    const size_t pbuf_b = (size_t)(NSPLIT + 1) * n4 * 8;
    const size_t need = off_pbuf + pbuf_b;

    const int block = 256;
    const bool shape_ok = (B <= MAXB) && (E > 0) && (E < (1 << 22));

    if (shape_ok && coop_state == 1 && need2 <= ws_size) {
        unsigned int* idbuf = (unsigned int*)d_ws;
        unsigned int* cnt   = (unsigned int*)((char*)d_ws + off_cnt2);
        unsigned long long* pbuf = (unsigned long long*)((char*)d_ws + off_pbuf2);
        unsigned long long* spill = pbuf + (size_t)NSPLIT2 * n4;

        hipMemsetAsync(spill, 0, (size_t)n4 * 8, stream);

        int per_block2 = (E + FB - 1) / FB;
        per_block2 = (per_block2 + 1) & ~1;   // even, for int2 loads

        int E_ = E, B_ = B, N_ = N, cap_ = capb2, pb_ = per_block2;
        void* kargs[] = { (void*)&edge, (void*)&ew, (void*)&idbuf, (void*)&cnt,
                          (void*)&pbuf, (void*)&out,
                          (void*)&E_, (void*)&B_, (void*)&cap_, (void*)&pb_, (void*)&N_ };
        hipError_t lr = hipLaunchCooperativeKernel(
            spmm_fused, dim3(FB), dim3(FT), kargs, 0, stream);
        if (lr == hipSuccess) return;
        coop_state = 0;  // fall through to binned path next
    }

    if (shape_ok && need <= ws_size) {
        unsigned int* idbuf = (unsigned int*)d_ws;
        unsigned int* cnt   = (unsigned int*)((char*)d_ws + off_cnt);
        unsigned long long* pbuf  = (unsigned long long*)((char*)d_ws + off_pbuf);
        unsigned long long* spill = pbuf + (size_t)NSPLIT * n4;

        hipMemsetAsync(spill, 0, (size_t)n4 * 8, stream);

        const int per_block = (E + NBIN - 1) / NBIN;
        spmm_bin_id<<<NBIN, BINT, 0, stream>>>(edge, ew, idbuf, cnt, spill,
                                               E, B, capb, per_block);
        spmm_acc_g<<<B * NSPLIT, ACCT, 0, stream>>>(ew, idbuf, cnt, pbuf,
                                                    B, capb, N);
        spmm_decode9<<<(n4 + block - 1) / block, block, 0, stream>>>(pbuf, out, n4);
    } else {
        unsigned long long* ws = (unsigned long long*)d_ws;
        hipMemsetAsync(ws, 0, (size_t)n4 * 8, stream);
        spmm_scatter_gs<<<2048, block, 0, stream>>>(edge, ew, ws, E * 4);
        spmm_decode1<<<(n4 + block - 1) / block, block, 0, stream>>>(ws, out, n4);
    }
}

// Round 3
// 355.228 us; speedup vs baseline: 1.0011x; 1.0011x over previous
//
#include <hip/hip_runtime.h>
#include <hip/hip_cooperative_groups.h>
#include <math.h>

namespace cg = cooperative_groups;

// Segment-sum out[src[e], f] += edge_w[e][f], E=3.2M, N=100k, F=16.
//
// R2 counters (fused, 512 blocks): VALUBusy 3.2%, HBM 6%, Occupancy 48.6%
// -> latency-bound, concurrency-starved. Fixes:
//  * FB=1024 blocks (4/CU, LDS-limited max) -> occupancy ~97%; acc's 784
//    tasks < 1024 blocks -> single round (was 2 rounds at 53% util).
//  * acc: wave = 1 slice x 16 slots x 4 quads -> idbuf reads stay 1-line
//    coalesced; 4x unrolled slot-rounds fit the 64-VGPR budget (R2's 8x
//    unroll needed ~56 live VGPRs and was silently serialized);
//    per-lane predication (slot<k) instead of clamped garbage gathers.
//  * capb ladder (6 sigma, auto-shrunk to fit ws) so the 1024-region idbuf
//    can't trip the ws gate into the slow fallback; overflow -> fabric
//    spill slice (correct, ~0.4 edges/run at 4 sigma).

#define F 16
#define NPB 1024
#define NPB_SHIFT 10
#define MAXB 128
#define SCALE 256.0f
#define INV_SCALE (1.0f / 256.0f)

// ---- fallback (R6-verified) config ----
#define NBIN 256
#define BINT 512
#define NSPLIT 8
#define SLICES (NBIN / NSPLIT)
#define ACCT 512

// ---- fused config ----
#define FB 1024                      // grid blocks (4/CU on 256 CUs)
#define FT 512                       // threads per block
#define NBIN2 1024                   // bin regions == FB
#define NSPLIT2 8
#define SLICES2 (NBIN2 / NSPLIT2)    // 128

__device__ __forceinline__ unsigned long long qpack(float4 v) {
    long long q0 = (long long)__float2int_rn(v.x * SCALE);
    long long q1 = (long long)__float2int_rn(v.y * SCALE);
    long long q2 = (long long)__float2int_rn(v.z * SCALE);
    long long q3 = (long long)__float2int_rn(v.w * SCALE);
    return (unsigned long long)((q3 << 48) + (q2 << 32) + (q1 << 16) + q0);
}

// ================================================================ fused
__global__ __launch_bounds__(FT, 8) void spmm_fused(
    const int* __restrict__ src,
    const float* __restrict__ w,
    unsigned int* __restrict__ idbuf,        // [NBIN2][B][capb]
    unsigned int* __restrict__ cnt,          // [NBIN2][B]
    unsigned long long* __restrict__ pbuf,   // [NSPLIT2+1][n4], last = spill
    float* __restrict__ out,
    int E, int B, int capb, int per_block, int N)
{
    __shared__ unsigned long long acc[NPB * 4];  // 32 KB
    __shared__ unsigned int pos[MAXB];
    __shared__ unsigned int ksh[SLICES2];

    cg::grid_group grid = cg::this_grid();
    const int tid = threadIdx.x;
    const int bid = blockIdx.x;
    const int n4  = N * 4;
    unsigned long long* spill = pbuf + (size_t)NSPLIT2 * (size_t)n4;

    // ---------------- phase 1: bin ----------------
    for (int i = tid; i < B; i += FT) pos[i] = 0;
    __syncthreads();

    const int lo = bid * per_block;
    const int hi = min(E, lo + per_block);
    for (int e = lo + tid * 2; e < hi; e += FT * 2) {
        int sa, sb = -1;
        if (e + 1 < hi) { int2 s2 = *(const int2*)(src + e); sa = s2.x; sb = s2.y; }
        else            { sa = src[e]; }
        {
            const int bk = sa >> NPB_SHIFT;
            const unsigned int off = (unsigned int)(sa & (NPB - 1));
            const unsigned int r = atomicAdd(&pos[bk], 1u);
            if (r < (unsigned int)capb) {
                idbuf[((size_t)bid * B + bk) * capb + r] = (off << 22) | (unsigned int)e;
            } else {
                const float4* wr = (const float4*)(w + (size_t)e * F);
                #pragma unroll
                for (int qq = 0; qq < 4; ++qq)
                    atomicAdd(&spill[(size_t)sa * 4 + qq], qpack(wr[qq]));
            }
        }
        if (sb >= 0) {
            const int e1 = e + 1;
            const int bk = sb >> NPB_SHIFT;
            const unsigned int off = (unsigned int)(sb & (NPB - 1));
            const unsigned int r = atomicAdd(&pos[bk], 1u);
            if (r < (unsigned int)capb) {
                idbuf[((size_t)bid * B + bk) * capb + r] = (off << 22) | (unsigned int)e1;
            } else {
                const float4* wr = (const float4*)(w + (size_t)e1 * F);
                #pragma unroll
                for (int qq = 0; qq < 4; ++qq)
                    atomicAdd(&spill[(size_t)sb * 4 + qq], qpack(wr[qq]));
            }
        }
    }
    __syncthreads();
    for (int i = tid; i < B; i += FT)
        cnt[bid * B + i] = min(pos[i], (unsigned int)capb);

    __threadfence();   // device-scope: idbuf/cnt visible cross-XCD
    grid.sync();

    // ---------------- phase 2: acc ----------------
    // tasks = B*NSPLIT2 = 784 <= FB -> single round.
    // wave = 1 slice x 16 slots x 4 quads: idbuf reads 1-line coalesced.
    const int q   = tid & 3;          // feature quad
    const int st  = tid >> 2;         // slot-thread 0..127
    const int sg  = st >> 4;          // slice subgroup 0..7
    const int s16 = st & 15;          // slot-within-16

    for (int t = bid; t < B * NSPLIT2; t += FB) {
        const int b  = t >> 3;
        const int sp = t & 7;

        for (int i = tid; i < NPB * 4; i += FT) acc[i] = 0ULL;
        if (tid < SLICES2) ksh[tid] = cnt[(sp * SLICES2 + tid) * B + b];
        __syncthreads();

        for (int sr = 0; sr < 16; ++sr) {
            const int s   = sr * 8 + sg;               // slice 0..127
            const int blk = sp * SLICES2 + s;
            const unsigned int k = ksh[s];
            const unsigned int* cell = idbuf + ((size_t)blk * B + b) * capb;
            #pragma unroll
            for (int tr = 0; tr < 4; ++tr) {           // slots 0..63
                const unsigned int slot = (unsigned int)(tr * 16 + s16);
                if (slot < k) {
                    const unsigned int entry = cell[slot];
                    const unsigned int off = entry >> 22;
                    const unsigned int e   = entry & 0x3FFFFFu;
                    const float4 v = *(const float4*)(w + (size_t)e * F + q * 4);
                    atomicAdd(&acc[off * 4 + q], qpack(v));
                }
            }
        }
        // rare tail: slots >= 64 (capb may exceed 64); st <-> slice 1:1
        {
            const int s = st;
            const unsigned int k = ksh[s];
            if (k > 64u) {
                const int blk = sp * SLICES2 + s;
                const unsigned int* cell = idbuf + ((size_t)blk * B + b) * capb;
                for (unsigned int i = 64u; i < k; ++i) {
                    const unsigned int entry = cell[i];
                    const unsigned int off = entry >> 22;
                    const unsigned int e   = entry & 0x3FFFFFu;
                    const float4 v = *(const float4*)(w + (size_t)e * F + q * 4);
                    atomicAdd(&acc[off * 4 + q], qpack(v));
                }
            }
        }
        __syncthreads();

        const int nbase = b << NPB_SHIFT;
        const int lim = min(NPB, N - nbase);
        unsigned long long* dst = pbuf + (size_t)sp * n4 + (size_t)nbase * 4;
        for (int i = tid; i < lim * 4; i += FT) dst[i] = acc[i];
        __syncthreads();
    }

    __threadfence();
    grid.sync();

    // ---------------- phase 3: decode ----------------
    for (int idx = bid * FT + tid; idx < n4; idx += FB * FT) {
        unsigned long long a = 0;
        #pragma unroll
        for (int s = 0; s < NSPLIT2 + 1; ++s) a += pbuf[(size_t)s * n4 + idx];
        long long tt = (long long)a;
        const int s0 = (int)(short)(tt & 0xffff);  tt = (tt - s0) >> 16;
        const int s1 = (int)(short)(tt & 0xffff);  tt = (tt - s1) >> 16;
        const int s2 = (int)(short)(tt & 0xffff);  tt = (tt - s2) >> 16;
        const int s3 = (int)(short)(tt & 0xffff);
        float4 o;
        o.x = (float)s0 * INV_SCALE;
        o.y = (float)s1 * INV_SCALE;
        o.z = (float)s2 * INV_SCALE;
        o.w = (float)s3 * INV_SCALE;
        ((float4*)out)[idx] = o;
    }
}

// ======================================================= fallback kernels
__global__ __launch_bounds__(BINT) void spmm_bin_id(
    const int* __restrict__ src,
    const float* __restrict__ w,
    unsigned int* __restrict__ idbuf,
    unsigned int* __restrict__ cnt,
    unsigned long long* __restrict__ spill,
    int E, int B, int capb, int per_block)
{
    __shared__ unsigned int pos[MAXB];
    const int tid = threadIdx.x;
    for (int i = tid; i < B; i += BINT) pos[i] = 0;
    __syncthreads();

    const int lo = blockIdx.x * per_block;
    const int hi = min(E, lo + per_block);

    for (int e = lo + tid; e < hi; e += BINT) {
        const int s = src[e];
        const int bk = s >> NPB_SHIFT;
        const unsigned int off = (unsigned int)(s & (NPB - 1));
        const unsigned int r = atomicAdd(&pos[bk], 1u);
        if (r < (unsigned int)capb) {
            idbuf[((size_t)blockIdx.x * B + bk) * capb + r] =
                (off << 22) | (unsigned int)e;
        } else {
            const float4* wr = (const float4*)(w + (size_t)e * F);
            #pragma unroll
            for (int q = 0; q < 4; ++q)
                atomicAdd(&spill[(size_t)s * 4 + q], qpack(wr[q]));
        }
    }
    __syncthreads();
    for (int i = tid; i < B; i += BINT)
        cnt[blockIdx.x * B + i] = min(pos[i], (unsigned int)capb);
}

__global__ __launch_bounds__(ACCT) void spmm_acc_g(
    const float* __restrict__ w,
    const unsigned int* __restrict__ idbuf,
    const unsigned int* __restrict__ cnt,
    unsigned long long* __restrict__ pbuf,
    int B, int capb, int N)
{
    __shared__ unsigned long long acc[NPB * 4];
    const int tid = threadIdx.x;
    const int b  = blockIdx.x >> 3;
    const int sp = blockIdx.x & 7;

    for (int i = tid; i < NPB * 4; i += ACCT) acc[i] = 0ULL;
    __syncthreads();

    const int q  = tid & 3;
    const int ei = tid >> 2;

    for (int sl = 0; sl < SLICES; ++sl) {
        const int blk = sp * SLICES + sl;
        const unsigned int k = cnt[blk * B + b];
        const unsigned int* base = idbuf + ((size_t)blk * B + b) * capb;
        for (unsigned int i = ei; i < k; i += ACCT / 4) {
            const unsigned int entry = base[i];
            const unsigned int off = entry >> 22;
            const unsigned int e   = entry & 0x3FFFFFu;
            const float4 v = *(const float4*)(w + (size_t)e * F + q * 4);
            atomicAdd(&acc[off * 4 + q], qpack(v));
        }
    }
    __syncthreads();

    const int nbase = b << NPB_SHIFT;
    const int lim = min(NPB, N - nbase);
    unsigned long long* dst = pbuf + (size_t)sp * ((size_t)N * 4) + (size_t)nbase * 4;
    for (int i = tid; i < lim * 4; i += ACCT) dst[i] = acc[i];
}

__global__ __launch_bounds__(256) void spmm_decode9(
    const unsigned long long* __restrict__ pbuf,
    float* __restrict__ out, int n4)
{
    const int idx = blockIdx.x * 256 + threadIdx.x;
    if (idx >= n4) return;
    unsigned long long a = 0;
    #pragma unroll
    for (int s = 0; s < NSPLIT + 1; ++s) a += pbuf[(size_t)s * n4 + idx];

    long long t = (long long)a;
    const int s0 = (int)(short)(t & 0xffff);  t = (t - s0) >> 16;
    const int s1 = (int)(short)(t & 0xffff);  t = (t - s1) >> 16;
    const int s2 = (int)(short)(t & 0xffff);  t = (t - s2) >> 16;
    const int s3 = (int)(short)(t & 0xffff);

    float4 o;
    o.x = (float)s0 * INV_SCALE;
    o.y = (float)s1 * INV_SCALE;
    o.z = (float)s2 * INV_SCALE;
    o.w = (float)s3 * INV_SCALE;
    ((float4*)out)[idx] = o;
}

__global__ __launch_bounds__(256) void spmm_scatter_gs(
    const int* __restrict__ src,
    const float* __restrict__ w,
    unsigned long long* __restrict__ ws,
    int total)
{
    const int stride = gridDim.x * blockDim.x;
    for (int idx = blockIdx.x * blockDim.x + threadIdx.x; idx < total; idx += stride) {
        const int e = idx >> 2, lane = idx & 3;
        const float4 v = ((const float4*)w)[idx];
        atomicAdd(&ws[src[e] * 4 + lane], qpack(v));
    }
}

__global__ __launch_bounds__(256) void spmm_decode1(
    const unsigned long long* __restrict__ ws,
    float* __restrict__ out, int n4)
{
    const int idx = blockIdx.x * 256 + threadIdx.x;
    if (idx >= n4) return;
    long long t = (long long)ws[idx];
    const int s0 = (int)(short)(t & 0xffff);  t = (t - s0) >> 16;
    const int s1 = (int)(short)(t & 0xffff);  t = (t - s1) >> 16;
    const int s2 = (int)(short)(t & 0xffff);  t = (t - s2) >> 16;
    const int s3 = (int)(short)(t & 0xffff);
    float4 o;
    o.x = (float)s0 * INV_SCALE;
    o.y = (float)s1 * INV_SCALE;
    o.z = (float)s2 * INV_SCALE;
    o.w = (float)s3 * INV_SCALE;
    ((float4*)out)[idx] = o;
}

// ---------------------------------------------------------------- launch
extern "C" void kernel_launch(void* const* d_in, const int* in_sizes, int n_in,
                              void* d_out, int out_size, void* d_ws, size_t ws_size,
                              hipStream_t stream) {
    const int* edge = (const int*)d_in[0];    // (2, E) -- row 0 is src
    const float* ew = (const float*)d_in[1];  // (E, 16)
    const int E = in_sizes[0] / 2;
    const int N = out_size / F;
    const int n4 = N * 4;
    float* out = (float*)d_out;

    const int B = (N + NPB - 1) >> NPB_SHIFT;  // 98

    // one-time cooperative-capability probe (host-only; capture-safe)
    static int coop_state = -1;
    if (coop_state < 0) {
        int maxb = 0, cus = 0;
        hipDeviceProp_t prop;
        int dev = 0;
        hipError_t e1 = hipGetDevice(&dev);
        hipError_t e2 = hipGetDeviceProperties(&prop, dev);
        if (e2 == hipSuccess) cus = prop.multiProcessorCount;
        hipError_t e3 = hipOccupancyMaxActiveBlocksPerMultiprocessor(
            &maxb, spmm_fused, FT, 0);
        coop_state = (e1 == hipSuccess && e3 == hipSuccess &&
                      (long)maxb * (long)cus >= FB) ? 1 : 0;
    }

    // ---- fused path layout (capb ladder: 6-sigma preferred, shrink to fit ws) ----
    const double mean2 = (double)E / ((double)NBIN2 * (double)B);   // ~31.9
    const double sig2  = sqrt(mean2 > 1.0 ? mean2 : 1.0);
    int capb2 = (int)(mean2 + 6.0 * sig2 + 8.0);
    capb2 = (capb2 + 15) & ~15;                                     // ~80
    const size_t cnt2_b  = (size_t)NBIN2 * B * 4;
    const size_t pbuf2_b = (size_t)(NSPLIT2 + 1) * n4 * 8;          // ~28.8 MB
    const size_t fixed2  = ((cnt2_b + 255) & ~(size_t)255) + pbuf2_b + 512;
    if (ws_size > fixed2) {
        const size_t idroom = ws_size - fixed2;
        int capb2_max = (int)(idroom / ((size_t)NBIN2 * B * 4));
        capb2_max &= ~15;
        if (capb2 > capb2_max) capb2 = capb2_max;                   // shrink to fit
    }
    const int capb2_min = ((int)(mean2 + 3.0 * sig2) + 15) & ~15;   // sanity floor
    const size_t idbuf2_b = (size_t)NBIN2 * B * capb2 * 4;
    size_t off_cnt2  = (idbuf2_b + 255) & ~(size_t)255;
    size_t off_pbuf2 = (off_cnt2 + cnt2_b + 255) & ~(size_t)255;
    const size_t need2 = off_pbuf2 + pbuf2_b;

    // ---- fallback binned layout ----
    const double mean = (double)E / ((double)NBIN * (double)B);
    int capb = (int)(mean + 8.0 * sqrt(mean > 1.0 ? mean : 1.0) + 16.0);
    capb = (capb + 15) & ~15;
    const size_t idbuf_b = (size_t)NBIN * B * capb * 4;
    size_t off_cnt  = (idbuf_b + 255) & ~(size_t)255;
    const size_t cnt_b = (size_t)NBIN * B * 4;
    size_t off_pbuf = (off_cnt + cnt_b + 255) & ~(size_t)255;
    const size_t pbuf_b = (size_t)(NSPLIT + 1) * n4 * 8;
    const size_t need = off_pbuf + pbuf_b;

    const int block = 256;
    const bool shape_ok = (B <= MAXB) && (E > 0) && (E < (1 << 22));

    if (shape_ok && coop_state == 1 && capb2 >= capb2_min && capb2 >= 16 &&
        need2 <= ws_size) {
        unsigned int* idbuf = (unsigned int*)d_ws;
        unsigned int* cnt   = (unsigned int*)((char*)d_ws + off_cnt2);
        unsigned long long* pbuf = (unsigned long long*)((char*)d_ws + off_pbuf2);
        unsigned long long* spill = pbuf + (size_t)NSPLIT2 * n4;

        hipMemsetAsync(spill, 0, (size_t)n4 * 8, stream);

        int per_block2 = (E + FB - 1) / FB;
        per_block2 = (per_block2 + 1) & ~1;   // even, for int2 loads

        int E_ = E, B_ = B, N_ = N, cap_ = capb2, pb_ = per_block2;
        void* kargs[] = { (void*)&edge, (void*)&ew, (void*)&idbuf, (void*)&cnt,
                          (void*)&pbuf, (void*)&out,
                          (void*)&E_, (void*)&B_, (void*)&cap_, (void*)&pb_, (void*)&N_ };
        hipError_t lr = hipLaunchCooperativeKernel(
            spmm_fused, dim3(FB), dim3(FT), kargs, 0, stream);
        if (lr == hipSuccess) return;
        coop_state = 0;  // fall through to binned path next
    }

    if (shape_ok && need <= ws_size) {
        unsigned int* idbuf = (unsigned int*)d_ws;
        unsigned int* cnt   = (unsigned int*)((char*)d_ws + off_cnt);
        unsigned long long* pbuf  = (unsigned long long*)((char*)d_ws + off_pbuf);
        unsigned long long* spill = pbuf + (size_t)NSPLIT * n4;

        hipMemsetAsync(spill, 0, (size_t)n4 * 8, stream);

        const int per_block = (E + NBIN - 1) / NBIN;
        spmm_bin_id<<<NBIN, BINT, 0, stream>>>(edge, ew, idbuf, cnt, spill,
                                               E, B, capb, per_block);
        spmm_acc_g<<<B * NSPLIT, ACCT, 0, stream>>>(ew, idbuf, cnt, pbuf,
                                                    B, capb, N);
        spmm_decode9<<<(n4 + block - 1) / block, block, 0, stream>>>(pbuf, out, n4);
    } else {
        unsigned long long* ws = (unsigned long long*)d_ws;
        hipMemsetAsync(ws, 0, (size_t)n4 * 8, stream);
        spmm_scatter_gs<<<2048, block, 0, stream>>>(edge, ew, ws, E * 4);
        spmm_decode1<<<(n4 + block - 1) / block, block, 0, stream>>>(ws, out, n4);
    }
}